// Round 1
// baseline (185.165 us; speedup 1.0000x reference)
//
#include <hip/hip_runtime.h>

#define B_TOT 65536
#define R 12
#define L 16
#define F 8
#define NB 16            // batches per block
#define BH_LSTRIDE 36    // floats per led row in LDS (32 + pad, 16B-aligned)
#define BH_BSTRIDE 580   // floats per batch in LDS (16*36 + 4 pad -> bank spread, 16B-aligned)
#define NEG_MIN -3.402823466e38f

// Workspace layout (floats):
// [0,1024)    M[i*32+j] = sum_h qw2[i,h]*kw2[j,h]
// [1024,1056) u[i] = sum_h qw2[i,h]*kb2[h]
// [1056,1088) v[j] = sum_h kw2[j,h]*qb2[h]
// [1088]      c    = sum_h qb2[h]*kb2[h]

__global__ __launch_bounds__(256) void nfh_precompute(
    const float* __restrict__ qw2, const float* __restrict__ qb2,
    const float* __restrict__ kw2, const float* __restrict__ kb2,
    float* __restrict__ ws)
{
    const int t = threadIdx.x;
    for (int e = t; e < 1024; e += 256) {
        const int i = e >> 5, j = e & 31;
        float acc = 0.f;
        for (int h = 0; h < 64; ++h) acc = fmaf(qw2[i * 64 + h], kw2[j * 64 + h], acc);
        ws[e] = acc;
    }
    if (t < 32) {
        float acc = 0.f;
        for (int h = 0; h < 64; ++h) acc = fmaf(qw2[t * 64 + h], kb2[h], acc);
        ws[1024 + t] = acc;
    } else if (t < 64) {
        const int j = t - 32;
        float acc = 0.f;
        for (int h = 0; h < 64; ++h) acc = fmaf(kw2[j * 64 + h], qb2[h], acc);
        ws[1056 + j] = acc;
    } else if (t == 64) {
        float acc = 0.f;
        for (int h = 0; h < 64; ++h) acc = fmaf(qb2[h], kb2[h], acc);
        ws[1088] = acc;
    }
}

__global__ __launch_bounds__(256) void nfh_main(
    const float* __restrict__ rss,   // [B,R]
    const float* __restrict__ feat,  // [B,L,F]
    const float* __restrict__ pos,   // [B,L,3]
    const float* __restrict__ prev,  // [B,3]
    const int*   __restrict__ fmask, // [R,L]
    const float* __restrict__ gw1, const float* __restrict__ gb1,
    const float* __restrict__ gw2, const float* __restrict__ gb2,
    const float* __restrict__ qw1, const float* __restrict__ qb1,
    const float* __restrict__ kw1, const float* __restrict__ kb1,
    const float* __restrict__ sigma_p,
    const float* __restrict__ ws,
    float* __restrict__ out)
{
    __shared__ float s_bh[NB * BH_BSTRIDE]; // key hiddens, padded
    __shared__ float s_vb[NB * L];          // v.b + c - dist^2/(2s^2) per (bb,l)

    const int t = threadIdx.x;
    const int b0 = blockIdx.x * NB;
    const float sigma = sigma_p[0];
    const float inv2s2 = 1.f / (2.f * sigma * sigma);
    const float* __restrict__ Mw = ws;
    const float* __restrict__ uw = ws + 1024;
    const float* __restrict__ vw = ws + 1056;
    const float cc = ws[1088];

    // ---------------- Phase 1: thread = (bb, l) — key hidden b_l ----------------
    {
        const int bb = t >> 4, l = t & 15;
        const int b = b0 + bb;
        float in[11];
        const float4* f4 = (const float4*)(feat + ((size_t)b * (L * F) + l * F));
        float4 fa = f4[0], fb = f4[1];
        in[0] = fa.x; in[1] = fa.y; in[2] = fa.z; in[3] = fa.w;
        in[4] = fb.x; in[5] = fb.y; in[6] = fb.z; in[7] = fb.w;
        const float* pp = pos + ((size_t)b * (L * 3) + l * 3);
        in[8] = pp[0]; in[9] = pp[1]; in[10] = pp[2];

        float dsq = 0.f;
        #pragma unroll
        for (int m = 0; m < 3; ++m) {
            float d = prev[b * 3 + m] - in[8 + m];
            dsq = fmaf(d, d, dsq);
        }

        float bh[32];
        #pragma unroll
        for (int j = 0; j < 32; ++j) bh[j] = kb1[j];
        #pragma unroll
        for (int m = 0; m < 11; ++m) {
            const float im = in[m];
            #pragma unroll
            for (int j = 0; j < 32; ++j) bh[j] = fmaf(im, kw1[m * 32 + j], bh[j]);
        }
        float vb = 0.f;
        #pragma unroll
        for (int j = 0; j < 32; ++j) {
            bh[j] = fmaxf(bh[j], 0.f);
            vb = fmaf(vw[j], bh[j], vb);
        }
        s_vb[bb * L + l] = vb + cc - dsq * inv2s2;

        float4* dst = (float4*)&s_bh[bb * BH_BSTRIDE + l * BH_LSTRIDE];
        #pragma unroll
        for (int q = 0; q < 8; ++q)
            dst[q] = make_float4(bh[q * 4], bh[q * 4 + 1], bh[q * 4 + 2], bh[q * 4 + 3]);
    }
    __syncthreads();

    // ---------------- Phase 2: thread = (bb, r) — query side + scores + softmax ----
    if (t < NB * R) {
        const int bb = t / R;
        const int r = t - bb * R;
        const int b = b0 + bb;

        const float x = rss[(size_t)b0 * R + t]; // bb*R + r == t

        // intensity gate
        float z = gb2[0];
        #pragma unroll
        for (int i = 0; i < 16; ++i) {
            float h = fmaxf(fmaf(x, gw1[i], gb1[i]), 0.f);
            z = fmaf(h, gw2[i], z);
        }
        const float gate = 1.f / (1.f + __expf(-z));
        const float iw = (x > 0.5f) ? gate : 0.f;
        out[(size_t)B_TOT * R * L + (size_t)b0 * R + t] = iw;

        const float xq = x * iw;

        // query hidden a[i], plus d = a.u
        float a[32];
        float d = 0.f;
        #pragma unroll
        for (int i = 0; i < 32; ++i) {
            a[i] = fmaxf(fmaf(xq, qw1[i], qb1[i]), 0.f);
            d = fmaf(a[i], uw[i], d);
        }

        // t = a^T M  (M via uniform/scalar loads)
        float tt[32];
        #pragma unroll
        for (int j = 0; j < 32; ++j) tt[j] = 0.f;
        #pragma unroll 2
        for (int i = 0; i < 32; ++i) {
            const float ai = a[i];
            #pragma unroll
            for (int j = 0; j < 32; ++j) tt[j] = fmaf(ai, Mw[i * 32 + j], tt[j]);
        }

        // scores over 16 leds
        float sc[16];
        const float* bhp = &s_bh[bb * BH_BSTRIDE];
        #pragma unroll
        for (int l = 0; l < L; ++l) {
            const float4* bp4 = (const float4*)&bhp[l * BH_LSTRIDE];
            float acc = d + s_vb[bb * L + l];
            #pragma unroll
            for (int q = 0; q < 8; ++q) {
                float4 v4 = bp4[q];
                acc = fmaf(tt[q * 4 + 0], v4.x, acc);
                acc = fmaf(tt[q * 4 + 1], v4.y, acc);
                acc = fmaf(tt[q * 4 + 2], v4.z, acc);
                acc = fmaf(tt[q * 4 + 3], v4.w, acc);
            }
            sc[l] = (fmask[r * L + l] == 0) ? NEG_MIN : acc;
        }

        // softmax over l (matches jax: max-subtract; all-masked row -> uniform)
        float mx = sc[0];
        #pragma unroll
        for (int l = 1; l < L; ++l) mx = fmaxf(mx, sc[l]);
        float sum = 0.f;
        #pragma unroll
        for (int l = 0; l < L; ++l) {
            sc[l] = __expf(sc[l] - mx);
            sum += sc[l];
        }
        const float inv = 1.f / sum;

        float4* op4 = (float4*)(out + (size_t)((size_t)b * R + r) * L);
        #pragma unroll
        for (int q = 0; q < 4; ++q)
            op4[q] = make_float4(sc[q * 4] * inv, sc[q * 4 + 1] * inv,
                                 sc[q * 4 + 2] * inv, sc[q * 4 + 3] * inv);
    }
}

extern "C" void kernel_launch(void* const* d_in, const int* in_sizes, int n_in,
                              void* d_out, int out_size, void* d_ws, size_t ws_size,
                              hipStream_t stream) {
    const float* rss   = (const float*)d_in[0];
    const float* feat  = (const float*)d_in[1];
    const float* pos   = (const float*)d_in[2];
    const float* prev  = (const float*)d_in[3];
    const int*   fmask = (const int*)d_in[4];
    const float* gw1   = (const float*)d_in[5];
    const float* gb1   = (const float*)d_in[6];
    const float* gw2   = (const float*)d_in[7];
    const float* gb2   = (const float*)d_in[8];
    const float* qw1   = (const float*)d_in[9];
    const float* qb1   = (const float*)d_in[10];
    const float* qw2   = (const float*)d_in[11];
    const float* qb2   = (const float*)d_in[12];
    const float* kw1   = (const float*)d_in[13];
    const float* kb1   = (const float*)d_in[14];
    const float* kw2   = (const float*)d_in[15];
    const float* kb2   = (const float*)d_in[16];
    const float* sigma = (const float*)d_in[17];
    float* out = (float*)d_out;
    float* ws  = (float*)d_ws;

    nfh_precompute<<<1, 256, 0, stream>>>(qw2, qb2, kw2, kb2, ws);
    nfh_main<<<B_TOT / NB, 256, 0, stream>>>(
        rss, feat, pos, prev, fmask,
        gw1, gb1, gw2, gb2, qw1, qb1, kw1, kb1,
        sigma, ws, out);
}